// Round 5
// baseline (88.076 us; speedup 1.0000x reference)
//
#include <hip/hip_runtime.h>
#include <hip/hip_bf16.h>
#include <stdint.h>

#define SLOPE 0.2f

typedef short s16x8 __attribute__((ext_vector_type(8)));
typedef float f32x4 __attribute__((ext_vector_type(4)));

// gfx950 native packed f32->bf16 (RNE), one VALU op for two converts.
__device__ __forceinline__ uint32_t pk_bf16(float lo, float hi) {
    uint32_t r;
    asm("v_cvt_pk_bf16_f32 %0, %1, %2" : "=v"(r) : "v"(lo), "v"(hi));
    return r;
}

// ---------------------------------------------------------------------------
// Round-12: two changes vs round-11 (both in main_kernel scheduling):
//  (1) GEMM K-loop 16 iters x K=64  ->  8 iters x K=128 (barriers 16 -> 8),
//      same proven protocol: B global->reg distance-1 ahead of reg->LDS
//      staging, A regs distance-1, LDS = 2 buffers x 4 sub-slots of the
//      verified [64][40] geometry (40 KB). Per-acc MFMA k-order unchanged
//      (chunks ascend k) -> bitwise-identical output.
//  (2) row_start folded into edge blocks 128..143 (after edge stores,
//      tid<64, arithmetic verbatim) -> grid 272 -> 256, no second dispatch
//      wave behind the 256 CUs.
//   bx   0..127 : GEMM 64x64 tile
//   bx 128..255 : s_e edge scores (+ row_start on bx<144)
// attn_kernel: round-8 verbatim (replay-proven).
// ---------------------------------------------------------------------------
__global__ __launch_bounds__(256)
void main_kernel(const float* __restrict__ hmat,       // [1024][1024]
                 const float* __restrict__ adj,        // [16][64][64]
                 const float* __restrict__ edge_attr,  // [16384][128]
                 const float* __restrict__ W_node,     // [1024][512]
                 const float* __restrict__ W_edge,     // [128][512]
                 const float* __restrict__ w_attn,     // [192]
                 float* __restrict__ g,                // [1024][512]
                 float* __restrict__ s_e,              // [16384][8]
                 float* __restrict__ s_i,              // [1024][8]
                 float* __restrict__ s_j,              // [1024][8]
                 int* __restrict__ row_start)          // [1024]
{
    __shared__ __align__(16) char U[40960];
    unsigned short* Bs = (unsigned short*)U;   // [8 slots][64][40] = 40960 B
    float* wvs = (float*)U;                    // edge role overlay (4 KB)

    int bx = blockIdx.x, tid = threadIdx.x;

    if (bx < 128) {
        // ================= GEMM role =========================================
        int head = bx & 7, mt = bx >> 3;
        int n0 = head * 64, m0 = mt * 64;
        int wave = tid >> 6, lane = tid & 63;
        int l15 = lane & 15, quad = lane >> 4;
        int wv16 = wave * 16;

        int kp = tid >> 4, nq = tid & 15;      // B staging (transpose)

        const float* aFrag  = hmat + (size_t)(m0 + wv16 + l15) * 1024 + quad * 8;
        const float* bpBase = W_node + (size_t)(2 * kp) * 512 + n0 + nq * 4;

        f32x4 acc[4];
        #pragma unroll
        for (int i = 0; i < 4; ++i) acc[i] = (f32x4){0.f, 0.f, 0.f, 0.f};

        // A regs: tile `it` (8 float4 = rows of 4 k-chunks)
        float4 a0, a1, a2, a3, a4, a5, a6, a7;
        // B regs: tile `it+1` in flight (pairs b{2c},b{2c+1} = rows 2kp,2kp+1 of chunk c)
        float4 b0, b1, b2, b3, b4, b5, b6, b7;

        // ---- prologue: tile 0 -> LDS slots 0..3; tile-1 B -> regs; tile-0 A
        {
            float4 t0, t1;
            #define STAGE0(C, OFF)                                             \
            {                                                                  \
                t0 = *(const float4*)(bpBase + (size_t)(OFF) * 512);           \
                t1 = *(const float4*)(bpBase + (size_t)(OFF) * 512 + 512);     \
                const float* q0 = &t0.x; const float* q1 = &t1.x;              \
                _Pragma("unroll")                                              \
                for (int u = 0; u < 4; ++u)                                    \
                    *(uint32_t*)&Bs[((C) * 64 + nq * 4 + u) * 40 + 2 * kp] =   \
                        pk_bf16(q0[u], q1[u]);                                 \
            }
            STAGE0(0, 0); STAGE0(1, 32); STAGE0(2, 64); STAGE0(3, 96);
            #undef STAGE0
        }
        {   // B regs <- tile 1 (rows 128..255)
            const float* bp = bpBase + (size_t)128 * 512;
            b0 = *(const float4*)(bp);             b1 = *(const float4*)(bp + 512);
            b2 = *(const float4*)(bp + 32 * 512);  b3 = *(const float4*)(bp + 33 * 512);
            b4 = *(const float4*)(bp + 64 * 512);  b5 = *(const float4*)(bp + 65 * 512);
            b6 = *(const float4*)(bp + 96 * 512);  b7 = *(const float4*)(bp + 97 * 512);
        }
        a0 = *(const float4*)(aFrag);       a1 = *(const float4*)(aFrag + 4);
        a2 = *(const float4*)(aFrag + 32);  a3 = *(const float4*)(aFrag + 36);
        a4 = *(const float4*)(aFrag + 64);  a5 = *(const float4*)(aFrag + 68);
        a6 = *(const float4*)(aFrag + 96);  a7 = *(const float4*)(aFrag + 100);
        __syncthreads();

        // ---- main loop: 8 iters of K=128 ------------------------------------
        for (int it = 0; it < 8; ++it) {
            int buf = it & 1;
            int sbase = buf * 4;

            // convert this tile's A (before the regs are overwritten)
            union { s16x8 v; uint32_t w[4]; } A0, A1, A2, A3;
            A0.w[0] = pk_bf16(a0.x, a0.y); A0.w[1] = pk_bf16(a0.z, a0.w);
            A0.w[2] = pk_bf16(a1.x, a1.y); A0.w[3] = pk_bf16(a1.z, a1.w);
            A1.w[0] = pk_bf16(a2.x, a2.y); A1.w[1] = pk_bf16(a2.z, a2.w);
            A1.w[2] = pk_bf16(a3.x, a3.y); A1.w[3] = pk_bf16(a3.z, a3.w);
            A2.w[0] = pk_bf16(a4.x, a4.y); A2.w[1] = pk_bf16(a4.z, a4.w);
            A2.w[2] = pk_bf16(a5.x, a5.y); A2.w[3] = pk_bf16(a5.z, a5.w);
            A3.w[0] = pk_bf16(a6.x, a6.y); A3.w[1] = pk_bf16(a6.z, a6.w);
            A3.w[2] = pk_bf16(a7.x, a7.y); A3.w[3] = pk_bf16(a7.z, a7.w);

            if (it < 7) {   // A regs <- tile it+1
                const float* ap = aFrag + (size_t)(it + 1) * 128;
                a0 = *(const float4*)(ap);       a1 = *(const float4*)(ap + 4);
                a2 = *(const float4*)(ap + 32);  a3 = *(const float4*)(ap + 36);
                a4 = *(const float4*)(ap + 64);  a5 = *(const float4*)(ap + 68);
                a6 = *(const float4*)(ap + 96);  a7 = *(const float4*)(ap + 100);
            }

            // MFMAs: chunks ascend k -> same accumulation order as before
            #define CHUNK(C, AU)                                               \
            {                                                                  \
                s16x8 af = AU.v;                                               \
                _Pragma("unroll")                                              \
                for (int nt = 0; nt < 4; ++nt) {                               \
                    s16x8 bf = *(const s16x8*)&Bs[((sbase + (C)) * 64 + nt * 16 + l15) * 40 + quad * 8]; \
                    acc[nt] = __builtin_amdgcn_mfma_f32_16x16x32_bf16(af, bf, acc[nt], 0, 0, 0); \
                }                                                              \
            }
            CHUNK(0, A0); CHUNK(1, A1); CHUNK(2, A2); CHUNK(3, A3);
            #undef CHUNK

            if (it < 7) {   // stage B(it+1) regs -> slots (buf^1)*4 ..+3
                int sb = (buf ^ 1) * 4;
                #define STG(C, BL, BH)                                         \
                {                                                              \
                    const float* q0 = &BL.x; const float* q1 = &BH.x;          \
                    _Pragma("unroll")                                          \
                    for (int u = 0; u < 4; ++u)                                \
                        *(uint32_t*)&Bs[((sb + (C)) * 64 + nq * 4 + u) * 40 + 2 * kp] = \
                            pk_bf16(q0[u], q1[u]);                             \
                }
                STG(0, b0, b1); STG(1, b2, b3); STG(2, b4, b5); STG(3, b6, b7);
                #undef STG
            }
            if (it + 2 < 8) {   // B regs <- tile it+2
                const float* bp = bpBase + (size_t)((it + 2) * 128) * 512;
                b0 = *(const float4*)(bp);             b1 = *(const float4*)(bp + 512);
                b2 = *(const float4*)(bp + 32 * 512);  b3 = *(const float4*)(bp + 33 * 512);
                b4 = *(const float4*)(bp + 64 * 512);  b5 = *(const float4*)(bp + 65 * 512);
                b6 = *(const float4*)(bp + 96 * 512);  b7 = *(const float4*)(bp + 97 * 512);
            }
            if (it < 7) __syncthreads();
        }

        // ============ epilogue (round-4 verbatim: g + fused s_i/s_j) =========
        float wi[4], wj[4];
        #pragma unroll
        for (int nt = 0; nt < 4; ++nt) {
            wi[nt] = w_attn[nt * 16 + l15];
            wj[nt] = w_attn[64 + nt * 16 + l15];
        }
        float pi[4], pj[4];
        #pragma unroll
        for (int reg = 0; reg < 4; ++reg) { pi[reg] = 0.f; pj[reg] = 0.f; }
        #pragma unroll
        for (int nt = 0; nt < 4; ++nt) {
            #pragma unroll
            for (int reg = 0; reg < 4; ++reg) {
                int gm = m0 + wv16 + quad * 4 + reg;
                int gn = n0 + nt * 16 + l15;
                g[(size_t)gm * 512 + gn] = acc[nt][reg];
                pi[reg] += acc[nt][reg] * wi[nt];
                pj[reg] += acc[nt][reg] * wj[nt];
            }
        }
        #pragma unroll
        for (int mask = 1; mask < 16; mask <<= 1) {
            #pragma unroll
            for (int reg = 0; reg < 4; ++reg) {
                pi[reg] += __shfl_xor(pi[reg], mask);
                pj[reg] += __shfl_xor(pj[reg], mask);
            }
        }
        if (l15 == 0) {
            #pragma unroll
            for (int reg = 0; reg < 4; ++reg) {
                int r = m0 + wv16 + quad * 4 + reg;
                s_i[(size_t)r * 8 + head] = pi[reg];
                s_j[(size_t)r * 8 + head] = pj[reg];
            }
        }
    } else {
        // ======== edge-score role (round-10 verbatim) ========================
        {
            int c = tid & 127, halfT = tid >> 7;
            const float* we = w_attn + 128;
            #pragma unroll
            for (int hh = 0; hh < 4; ++hh) {
                int h = halfT * 4 + hh;
                float s = 0.f;
                const float* row = W_edge + (size_t)c * 512 + h * 64;
                #pragma unroll 8
                for (int f = 0; f < 64; ++f) s += row[f] * we[f];
                wvs[c * 8 + h] = s;
            }
        }
        __syncthreads();
        int e = (bx - 128) * 128 + (tid >> 1);
        int half = tid & 1;
        const float4* erow = (const float4*)(edge_attr + (size_t)e * 128 + half * 64);
        f32x4 accl = {0.f, 0.f, 0.f, 0.f};
        f32x4 acch = {0.f, 0.f, 0.f, 0.f};
        for (int c4 = 0; c4 < 16; ++c4) {
            float4 v = erow[c4];
            #pragma unroll
            for (int u = 0; u < 4; ++u) {
                int c = half * 64 + c4 * 4 + u;
                f32x4 w0 = *(const f32x4*)&wvs[c * 8];
                f32x4 w1 = *(const f32x4*)&wvs[c * 8 + 4];
                float x = (u == 0) ? v.x : (u == 1) ? v.y : (u == 2) ? v.z : v.w;
                accl += x * w0;
                acch += x * w1;
            }
        }
        #pragma unroll
        for (int q = 0; q < 4; ++q) {
            accl[q] += __shfl_xor(accl[q], 1);
            acch[q] += __shfl_xor(acch[q], 1);
        }
        if (half == 0) {
            *(f32x4*)(s_e + (size_t)e * 8)     = accl;
            *(f32x4*)(s_e + (size_t)e * 8 + 4) = acch;
        }
        // ---- folded row_start role (blocks 128..143, arithmetic verbatim) ---
        if (bx < 144 && tid < 64) {
            int b = bx - 128;
            const float* row = adj + (size_t)b * 4096 + (size_t)tid * 64;
            int cnt = 0;
            #pragma unroll 8
            for (int j = 0; j < 64; ++j) cnt += (row[j] > 0.5f) ? 1 : 0;
            int inc = cnt;
            #pragma unroll
            for (int d = 1; d < 64; d <<= 1) {
                int u = __shfl_up(inc, d, 64);
                if (tid >= d) inc += u;
            }
            row_start[b * 64 + tid] = inc - cnt;
        }
    }
}

// ---------------------------------------------------------------------------
// attn: one block per (b,i). Round-8 version verbatim (replay-proven).
// ---------------------------------------------------------------------------
__global__ __launch_bounds__(256)
void attn_kernel(const float* __restrict__ g,          // [1024][512] fp32
                 const float* __restrict__ adj,        // [16][64][64]
                 const float* __restrict__ s_e,        // [16384][8]
                 const float* __restrict__ s_i,        // [1024][8]
                 const float* __restrict__ s_j,        // [1024][8]
                 const int*   __restrict__ row_start,  // [1024]
                 float* __restrict__ out)              // [1024][512]
{
    __shared__ float a_s[16][8];
    __shared__ int nbr[16];
    __shared__ int m_nb_s;

    int bi = blockIdx.x;
    int b = bi >> 6, i = bi & 63;
    int tid = threadIdx.x;

    if (tid < 16) nbr[tid] = 0;          // safe default for k >= m_nb (a=0 there)
    if (tid < 64) {
        float av = adj[(size_t)b * 4096 + (size_t)i * 64 + tid];
        unsigned long long m = __ballot(av > 0.5f);
        if (av > 0.5f) {
            int before = __popcll(m & ((1ull << tid) - 1ull));
            if (before < 16) nbr[before] = tid;
        }
        if (tid == 0) {
            int c = __popcll(m);
            m_nb_s = (c > 16) ? 16 : c;
        }
    }
    __syncthreads();

    int m_nb = m_nb_s;

    int c0 = tid * 2;
    int h = tid >> 5;
    float2 gv[16];
    #pragma unroll
    for (int k = 0; k < 16; ++k) {
        gv[k] = *(const float2*)(g + (size_t)(b * 64 + nbr[k]) * 512 + c0);
    }

    if (tid < 128) {
        int hh = tid >> 4, k = tid & 15;
        float v;
        if (k < m_nb) {
            int rs = row_start[bi];
            float se = s_e[(size_t)(b * 1024 + rs + k) * 8 + hh];
            float sj = s_j[(size_t)(b * 64 + nbr[k]) * 8 + hh];
            float si = s_i[(size_t)bi * 8 + hh];
            v = si + sj + se;
            v = (v >= 0.f) ? v : SLOPE * v;
        } else {
            v = -1e30f;
        }
        float mx = v;
        #pragma unroll
        for (int mask = 1; mask < 16; mask <<= 1)
            mx = fmaxf(mx, __shfl_xor(mx, mask));
        float e = (k < m_nb) ? __expf(v - mx) : 0.f;
        float ssum = e;
        #pragma unroll
        for (int mask = 1; mask < 16; mask <<= 1)
            ssum += __shfl_xor(ssum, mask);
        a_s[k][hh] = e / ssum;
    }
    __syncthreads();

    float o0 = 0.f, o1 = 0.f;
    #pragma unroll
    for (int k = 0; k < 16; ++k) {
        float ak = a_s[k][h];
        o0 += ak * gv[k].x;
        o1 += ak * gv[k].y;
    }
    out[(size_t)bi * 512 + c0]     = o0;
    out[(size_t)bi * 512 + c0 + 1] = o1;
}

// ---------------------------------------------------------------------------
extern "C" void kernel_launch(void* const* d_in, const int* in_sizes, int n_in,
                              void* d_out, int out_size, void* d_ws, size_t ws_size,
                              hipStream_t stream) {
    const float* h_in      = (const float*)d_in[0];   // (16,64,1024)
    const float* adj_mat   = (const float*)d_in[1];   // (16,64,64)
    const float* edge_attr = (const float*)d_in[2];   // (16,1024,128)
    const float* W_node    = (const float*)d_in[3];   // (1024,512)
    const float* W_edge    = (const float*)d_in[4];   // (128,512)
    const float* w_attn    = (const float*)d_in[5];   // (192,)
    float* out = (float*)d_out;                       // (16,64,512) fp32

    char* ws = (char*)d_ws;
    float* g         = (float*)(ws + 0x000000);       // 2 MB
    float* s_e       = (float*)(ws + 0x200000);       // 512 KB
    float* s_i       = (float*)(ws + 0x280000);       // 32 KB
    float* s_j       = (float*)(ws + 0x288000);       // 32 KB
    int*   row_start = (int*)  (ws + 0x290000);       // 4 KB

    main_kernel<<<256, 256, 0, stream>>>(h_in, adj_mat, edge_attr,
                                         W_node, W_edge, w_attn,
                                         g, s_e, s_i, s_j, row_start);
    attn_kernel<<<1024, 256, 0, stream>>>(g, adj_mat, s_e, s_i, s_j,
                                          row_start, out);
}